// Round 11
// baseline (185.416 us; speedup 1.0000x reference)
//
#include <hip/hip_runtime.h>

// Problem constants (from reference): B=16, T=512, D=8576.
#define N_ROWS 8192            // B*T
#define D_CH   8576
#define DV     (D_CH / 4)      // 2144 float4 columns
#define NCHUNKS_MAX 256        // stats row-chunks (32 rows each); halved if ws too small
#define NRED 16                // second-level partial count
#define APPLY_ROWS_PER_BLOCK 16
#define APPLY_ROW_CHUNKS (N_ROWS / APPLY_ROWS_PER_BLOCK)   // 512
#define EPSV 1e-5f
#define NOISE_STD 0.05f

typedef float f32x4 __attribute__((ext_vector_type(4)));

// ws layout (f32x4 units):
//   [0, nchunks*2*DV)        : level-1 partials; chunk c: sums at c*2*DV, sumsq at +DV
//   [.., + NRED*2*DV)        : level-2 partials (16 copies)
//   then scale4 [DV], shift4 [DV]
// NO atomics; no ws zeroing needed (every slot written unconditionally each call).

__global__ __launch_bounds__(256) void bn_partial_stats(
    const f32x4* __restrict__ x, f32x4* __restrict__ part, int rows_per_block)
{
    int vc = blockIdx.x * blockDim.x + threadIdx.x;   // vec-channel
    if (vc >= DV) return;
    size_t base = (size_t)blockIdx.y * rows_per_block * DV + vc;
    f32x4 s0 = (f32x4)0.f, s1 = (f32x4)0.f, s2 = (f32x4)0.f, s3 = (f32x4)0.f;
    f32x4 q0 = (f32x4)0.f, q1 = (f32x4)0.f, q2 = (f32x4)0.f, q3 = (f32x4)0.f;
    for (int r = 0; r < rows_per_block; r += 8) {
        size_t b = base + (size_t)r * DV;
        f32x4 v0 = x[b + 0 * (size_t)DV];
        f32x4 v1 = x[b + 1 * (size_t)DV];
        f32x4 v2 = x[b + 2 * (size_t)DV];
        f32x4 v3 = x[b + 3 * (size_t)DV];
        f32x4 v4 = x[b + 4 * (size_t)DV];
        f32x4 v5 = x[b + 5 * (size_t)DV];
        f32x4 v6 = x[b + 6 * (size_t)DV];
        f32x4 v7 = x[b + 7 * (size_t)DV];
        s0 += v0; q0 += v0 * v0;
        s1 += v1; q1 += v1 * v1;
        s2 += v2; q2 += v2 * v2;
        s3 += v3; q3 += v3 * v3;
        s0 += v4; q0 += v4 * v4;
        s1 += v5; q1 += v5 * v5;
        s2 += v6; q2 += v6 * v6;
        s3 += v7; q3 += v7 * v7;
    }
    f32x4 s = (s0 + s1) + (s2 + s3);
    f32x4 q = (q0 + q1) + (q2 + q3);
    size_t slot = (size_t)blockIdx.y * (2 * DV) + vc;
    part[slot]      = s;
    part[slot + DV] = q;
}

// Level-2 reduce: 144 blocks (9 x 16), each folds `factor` chunks for its channels.
__global__ __launch_bounds__(256) void bn_reduce(
    const f32x4* __restrict__ part, f32x4* __restrict__ part2, int factor)
{
    int vc = blockIdx.x * blockDim.x + threadIdx.x;
    if (vc >= DV) return;
    f32x4 s = (f32x4)0.f, q = (f32x4)0.f;
    int c0 = blockIdx.y * factor;
    for (int g = 0; g < factor; g += 2) {
        size_t b0 = (size_t)(c0 + g) * (2 * DV) + vc;
        size_t b1 = (size_t)(c0 + g + 1) * (2 * DV) + vc;
        f32x4 sa = part[b0], qa = part[b0 + DV];
        f32x4 sb = part[b1], qb = part[b1 + DV];
        s += sa + sb;
        q += qa + qb;
    }
    size_t o = (size_t)blockIdx.y * (2 * DV) + vc;
    part2[o]      = s;
    part2[o + DV] = q;
}

__global__ __launch_bounds__(256) void bn_finalize(
    const f32x4* __restrict__ part2,
    const f32x4* __restrict__ gamma4, const f32x4* __restrict__ beta4,
    f32x4* __restrict__ ws_scale, f32x4* __restrict__ ws_shift)
{
    int vc = blockIdx.x * blockDim.x + threadIdx.x;
    if (vc >= DV) return;
    f32x4 s = (f32x4)0.f, q = (f32x4)0.f;
#pragma unroll
    for (int c = 0; c < NRED; c += 4) {
        size_t b0 = (size_t)(c + 0) * (2 * DV) + vc;
        size_t b1 = (size_t)(c + 1) * (2 * DV) + vc;
        size_t b2 = (size_t)(c + 2) * (2 * DV) + vc;
        size_t b3 = (size_t)(c + 3) * (2 * DV) + vc;
        f32x4 sa = part2[b0], qa = part2[b0 + DV];
        f32x4 sb = part2[b1], qb = part2[b1 + DV];
        f32x4 sc_ = part2[b2], qc = part2[b2 + DV];
        f32x4 sd = part2[b3], qd = part2[b3 + DV];
        s += (sa + sb) + (sc_ + sd);
        q += (qa + qb) + (qc + qd);
    }
    const float invN = 1.0f / (float)N_ROWS;
    f32x4 mu = s * invN;
    f32x4 var = q * invN - mu * mu;
    f32x4 gm = gamma4[vc];
    f32x4 bt = beta4[vc];
    f32x4 sc;
    sc.x = gm.x * rsqrtf(var.x + EPSV);
    sc.y = gm.y * rsqrtf(var.y + EPSV);
    sc.z = gm.z * rsqrtf(var.z + EPSV);
    sc.w = gm.w * rsqrtf(var.w + EPSV);
    ws_scale[vc] = sc;
    ws_shift[vc] = bt - mu * sc;
}

__global__ __launch_bounds__(256) void bn_apply(
    const f32x4* __restrict__ x, const f32x4* __restrict__ noise,
    const f32x4* __restrict__ ws_scale4, const f32x4* __restrict__ ws_shift4,
    f32x4* __restrict__ out)
{
    int vc = blockIdx.x * blockDim.x + threadIdx.x;
    if (vc >= DV) return;
    f32x4 sc = ws_scale4[vc];
    f32x4 sh = ws_shift4[vc];
    size_t base = (size_t)blockIdx.y * APPLY_ROWS_PER_BLOCK * DV + vc;
#pragma unroll
    for (int h = 0; h < 2; ++h) {
        size_t b = base + (size_t)(h * 8) * DV;
        f32x4 xv[8], nv[8];
#pragma unroll
        for (int r = 0; r < 8; ++r) {
            xv[r] = x[b + (size_t)r * DV];                                   // cached: L3-resident
            nv[r] = __builtin_nontemporal_load(&noise[b + (size_t)r * DV]);  // stream once
        }
#pragma unroll
        for (int r = 0; r < 8; ++r) {
            f32x4 o = xv[r] * sc + sh + nv[r] * NOISE_STD;
            __builtin_nontemporal_store(o, &out[b + (size_t)r * DV]);        // never re-read
        }
    }
}

extern "C" void kernel_launch(void* const* d_in, const int* in_sizes, int n_in,
                              void* d_out, int out_size, void* d_ws, size_t ws_size,
                              hipStream_t stream) {
    const float* x     = (const float*)d_in[0];
    const float* noise = (const float*)d_in[1];
    const float* gamma = (const float*)d_in[2];
    const float* beta  = (const float*)d_in[3];
    float* out = (float*)d_out;

    // largest power-of-2 chunk count (>= NRED) whose footprint fits in ws
    int nchunks = NCHUNKS_MAX;
    while (nchunks > NRED &&
           ((size_t)(nchunks + NRED) * 2 * DV + 2 * DV) * sizeof(f32x4) > ws_size)
        nchunks >>= 1;
    int rows_per_block = N_ROWS / nchunks;

    f32x4* part     = (f32x4*)d_ws;
    f32x4* part2    = part + (size_t)nchunks * 2 * DV;
    f32x4* ws_scale = part2 + (size_t)NRED * 2 * DV;
    f32x4* ws_shift = ws_scale + DV;

    dim3 blk(256, 1, 1);
    dim3 grd_stats((DV + 255) / 256, nchunks, 1);            // 9 x 256
    bn_partial_stats<<<grd_stats, blk, 0, stream>>>((const f32x4*)x, part, rows_per_block);

    dim3 grd_red((DV + 255) / 256, NRED, 1);                 // 9 x 16
    bn_reduce<<<grd_red, blk, 0, stream>>>(part, part2, nchunks / NRED);

    dim3 grd_fin((DV + 255) / 256, 1, 1);                    // 9
    bn_finalize<<<grd_fin, blk, 0, stream>>>(part2, (const f32x4*)gamma, (const f32x4*)beta,
                                             ws_scale, ws_shift);

    dim3 grd_apply((DV + 255) / 256, APPLY_ROW_CHUNKS, 1);   // 9 x 512
    bn_apply<<<grd_apply, blk, 0, stream>>>((const f32x4*)x, (const f32x4*)noise,
                                            (const f32x4*)ws_scale, (const f32x4*)ws_shift,
                                            (f32x4*)out);
}

// Round 12
// 180.368 us; speedup vs baseline: 1.0280x; 1.0280x over previous
//
#include <hip/hip_runtime.h>

// Problem constants (from reference): B=16, T=512, D=8576.
#define N_ROWS 8192            // B*T
#define D_CH   8576
#define DV     (D_CH / 4)      // 2144 float4 columns
#define NCHUNKS_MAX 128        // stats row-chunks (64 rows each); halved if ws too small
#define NRED 16                // second-level partial count
#define APPLY_ROWS_PER_BLOCK 16
#define APPLY_ROW_CHUNKS (N_ROWS / APPLY_ROWS_PER_BLOCK)   // 512
#define EPSV 1e-5f
#define NOISE_STD 0.05f

typedef float f32x4 __attribute__((ext_vector_type(4)));

// ws layout (f32x4 units):
//   [0, nchunks*2*DV)        : level-1 partials; chunk c: sums at c*2*DV, sumsq at +DV
//   [.., + NRED*2*DV)        : level-2 partials (16 copies)
//   then scale4 [DV], shift4 [DV]
// NO atomics; no ws zeroing needed (every slot written unconditionally each call).

__global__ __launch_bounds__(256) void bn_partial_stats(
    const f32x4* __restrict__ x, f32x4* __restrict__ part, int rows_per_block)
{
    int vc = blockIdx.x * blockDim.x + threadIdx.x;   // vec-channel
    if (vc >= DV) return;
    size_t base = (size_t)blockIdx.y * rows_per_block * DV + vc;
    f32x4 s0 = (f32x4)0.f, s1 = (f32x4)0.f, s2 = (f32x4)0.f, s3 = (f32x4)0.f;
    f32x4 q0 = (f32x4)0.f, q1 = (f32x4)0.f, q2 = (f32x4)0.f, q3 = (f32x4)0.f;
    for (int r = 0; r < rows_per_block; r += 8) {
        size_t b = base + (size_t)r * DV;
        f32x4 v0 = x[b + 0 * (size_t)DV];
        f32x4 v1 = x[b + 1 * (size_t)DV];
        f32x4 v2 = x[b + 2 * (size_t)DV];
        f32x4 v3 = x[b + 3 * (size_t)DV];
        f32x4 v4 = x[b + 4 * (size_t)DV];
        f32x4 v5 = x[b + 5 * (size_t)DV];
        f32x4 v6 = x[b + 6 * (size_t)DV];
        f32x4 v7 = x[b + 7 * (size_t)DV];
        s0 += v0; q0 += v0 * v0;
        s1 += v1; q1 += v1 * v1;
        s2 += v2; q2 += v2 * v2;
        s3 += v3; q3 += v3 * v3;
        s0 += v4; q0 += v4 * v4;
        s1 += v5; q1 += v5 * v5;
        s2 += v6; q2 += v6 * v6;
        s3 += v7; q3 += v7 * v7;
    }
    f32x4 s = (s0 + s1) + (s2 + s3);
    f32x4 q = (q0 + q1) + (q2 + q3);
    size_t slot = (size_t)blockIdx.y * (2 * DV) + vc;
    part[slot]      = s;
    part[slot + DV] = q;
}

// Level-2 reduce: 144 blocks (9 x 16), each folds `factor` chunks for its channels.
__global__ __launch_bounds__(256) void bn_reduce(
    const f32x4* __restrict__ part, f32x4* __restrict__ part2, int factor)
{
    int vc = blockIdx.x * blockDim.x + threadIdx.x;
    if (vc >= DV) return;
    f32x4 s = (f32x4)0.f, q = (f32x4)0.f;
    int c0 = blockIdx.y * factor;
    for (int g = 0; g < factor; g += 2) {
        size_t b0 = (size_t)(c0 + g) * (2 * DV) + vc;
        size_t b1 = (size_t)(c0 + g + 1) * (2 * DV) + vc;
        f32x4 sa = part[b0], qa = part[b0 + DV];
        f32x4 sb = part[b1], qb = part[b1 + DV];
        s += sa + sb;
        q += qa + qb;
    }
    size_t o = (size_t)blockIdx.y * (2 * DV) + vc;
    part2[o]      = s;
    part2[o + DV] = q;
}

__global__ __launch_bounds__(256) void bn_finalize(
    const f32x4* __restrict__ part2,
    const f32x4* __restrict__ gamma4, const f32x4* __restrict__ beta4,
    f32x4* __restrict__ ws_scale, f32x4* __restrict__ ws_shift)
{
    int vc = blockIdx.x * blockDim.x + threadIdx.x;
    if (vc >= DV) return;
    f32x4 s = (f32x4)0.f, q = (f32x4)0.f;
#pragma unroll
    for (int c = 0; c < NRED; c += 4) {
        size_t b0 = (size_t)(c + 0) * (2 * DV) + vc;
        size_t b1 = (size_t)(c + 1) * (2 * DV) + vc;
        size_t b2 = (size_t)(c + 2) * (2 * DV) + vc;
        size_t b3 = (size_t)(c + 3) * (2 * DV) + vc;
        f32x4 sa = part2[b0], qa = part2[b0 + DV];
        f32x4 sb = part2[b1], qb = part2[b1 + DV];
        f32x4 sc_ = part2[b2], qc = part2[b2 + DV];
        f32x4 sd = part2[b3], qd = part2[b3 + DV];
        s += (sa + sb) + (sc_ + sd);
        q += (qa + qb) + (qc + qd);
    }
    const float invN = 1.0f / (float)N_ROWS;
    f32x4 mu = s * invN;
    f32x4 var = q * invN - mu * mu;
    f32x4 gm = gamma4[vc];
    f32x4 bt = beta4[vc];
    f32x4 sc;
    sc.x = gm.x * rsqrtf(var.x + EPSV);
    sc.y = gm.y * rsqrtf(var.y + EPSV);
    sc.z = gm.z * rsqrtf(var.z + EPSV);
    sc.w = gm.w * rsqrtf(var.w + EPSV);
    ws_scale[vc] = sc;
    ws_shift[vc] = bt - mu * sc;
}

__global__ __launch_bounds__(256) void bn_apply(
    const f32x4* __restrict__ x, const f32x4* __restrict__ noise,
    const f32x4* __restrict__ ws_scale4, const f32x4* __restrict__ ws_shift4,
    f32x4* __restrict__ out)
{
    int vc = blockIdx.x * blockDim.x + threadIdx.x;
    if (vc >= DV) return;
    f32x4 sc = ws_scale4[vc];
    f32x4 sh = ws_shift4[vc];
    size_t base = (size_t)blockIdx.y * APPLY_ROWS_PER_BLOCK * DV + vc;
#pragma unroll
    for (int h = 0; h < 2; ++h) {
        size_t b = base + (size_t)(h * 8) * DV;
        f32x4 xv[8], nv[8];
#pragma unroll
        for (int r = 0; r < 8; ++r) {
            xv[r] = x[b + (size_t)r * DV];                                   // cached: L3-resident
            nv[r] = __builtin_nontemporal_load(&noise[b + (size_t)r * DV]);  // stream once
        }
#pragma unroll
        for (int r = 0; r < 8; ++r) {
            f32x4 o = xv[r] * sc + sh + nv[r] * NOISE_STD;
            __builtin_nontemporal_store(o, &out[b + (size_t)r * DV]);        // never re-read
        }
    }
}

extern "C" void kernel_launch(void* const* d_in, const int* in_sizes, int n_in,
                              void* d_out, int out_size, void* d_ws, size_t ws_size,
                              hipStream_t stream) {
    const float* x     = (const float*)d_in[0];
    const float* noise = (const float*)d_in[1];
    const float* gamma = (const float*)d_in[2];
    const float* beta  = (const float*)d_in[3];
    float* out = (float*)d_out;

    // largest power-of-2 chunk count (>= NRED) whose footprint fits in ws
    int nchunks = NCHUNKS_MAX;
    while (nchunks > NRED &&
           ((size_t)(nchunks + NRED) * 2 * DV + 2 * DV) * sizeof(f32x4) > ws_size)
        nchunks >>= 1;
    int rows_per_block = N_ROWS / nchunks;

    f32x4* part     = (f32x4*)d_ws;
    f32x4* part2    = part + (size_t)nchunks * 2 * DV;
    f32x4* ws_scale = part2 + (size_t)NRED * 2 * DV;
    f32x4* ws_shift = ws_scale + DV;

    dim3 blk(256, 1, 1);
    dim3 grd_stats((DV + 255) / 256, nchunks, 1);            // 9 x 128
    bn_partial_stats<<<grd_stats, blk, 0, stream>>>((const f32x4*)x, part, rows_per_block);

    dim3 grd_red((DV + 255) / 256, NRED, 1);                 // 9 x 16
    bn_reduce<<<grd_red, blk, 0, stream>>>(part, part2, nchunks / NRED);

    dim3 grd_fin((DV + 255) / 256, 1, 1);                    // 9
    bn_finalize<<<grd_fin, blk, 0, stream>>>(part2, (const f32x4*)gamma, (const f32x4*)beta,
                                             ws_scale, ws_shift);

    dim3 grd_apply((DV + 255) / 256, APPLY_ROW_CHUNKS, 1);   // 9 x 512
    bn_apply<<<grd_apply, blk, 0, stream>>>((const f32x4*)x, (const f32x4*)noise,
                                            (const f32x4*)ws_scale, (const f32x4*)ws_shift,
                                            (f32x4*)out);
}